// Round 4
// baseline (245.030 us; speedup 1.0000x reference)
//
#include <hip/hip_runtime.h>
#include <hip/hip_bf16.h>

// Flash-attention fwd, block-causal packed docs. fp32 HBM, bf16 MFMA.
// B=1, H=8, D=128. R13 = R11 kernel (BR=64, 4 waves, 2 blocks/CU; proven
// 46.4us) + SPLIT-K on heavy q-blocks:
//  - q-blocks with n>8 tiles are computed by TWO blocks: piece0 = tiles
//    [0,n/2) (all-full, no diagonal), piece1 = [n/2,n) (diagonal+mask).
//    Longest serial chain 16 -> 8 tiles; grid 512 -> 1024 (idle twins for
//    n<=8 exit immediately). The <25% pipe utils of R11 show the chains
//    overlap headroom exists; this converts chain-latency into overlap.
//  - partial (m, l, O_unnorm) per piece -> d_ws; LAST-FINISHER MERGES
//    (atomicAdd counter, threadfence release/acquire): no spin, no
//    dispatch-order or XCD-coherence assumption.
//  - host gates split on ws_size (~51MB needed); fallback = exact R11 grid.
// Keeps: swapped-operand QK^T (lane owns one query), P-in-registers PV,
// prepacked bf16 K / key-permuted V^T in d_ws (XOR-swizzled, gll16
// direct-to-LDS staging: linear dest + pre-swizzled src + swizzled read),
// double buffer, 1 barrier/tile, setprio on MFMA clusters.

#define HD 128
#define BR 64
#define BC 64
#define MAXCHAIN 8

typedef __attribute__((ext_vector_type(8))) short short8;
typedef __attribute__((ext_vector_type(4))) float floatx4;

__device__ inline unsigned packbf2(float lo, float hi) {
    __hip_bfloat162 h2 = __float22bfloat162_rn(make_float2(lo, hi));
    return *reinterpret_cast<unsigned*>(&h2);   // low16 = lo, high16 = hi
}
__device__ inline short bfs(float f) {
    __hip_bfloat16 b = __float2bfloat16(f);
    return *reinterpret_cast<short*>(&b);
}

__device__ inline void gll16(const void* g, void* l) {
    __builtin_amdgcn_global_load_lds(
        (const __attribute__((address_space(1))) unsigned int*)g,
        (__attribute__((address_space(3))) unsigned int*)l, 16, 0, 0);
}

// ---------------- prepack: fp32 -> bf16, swizzled (as R12) ----------------
__global__ __launch_bounds__(256) void prepack(
    const float* __restrict__ K, const float* __restrict__ V,
    unsigned short* __restrict__ wsK, unsigned short* __restrict__ wsVT,
    int S)
{
    const int tid = threadIdx.x;
    const int nKblk = (8 * S) / 16;           // H*S*16 chunks / 256
    const int bid = blockIdx.x;
    if (bid < nKblk) {
        // K: one 16B output chunk (8 bf16 <- 8 fp32) per thread, coalesced.
        const int cid = bid * 256 + tid;
        const int row = cid >> 4;              // global row (h*S + r)
        const int c   = cid & 15;
        const float* src = K + (size_t)row * HD + c * 8;
        float4 f0 = *(const float4*)src;
        float4 f1 = *(const float4*)(src + 4);
        union { uint4 q; unsigned u[4]; } w;
        w.u[0] = packbf2(f0.x, f0.y); w.u[1] = packbf2(f0.z, f0.w);
        w.u[2] = packbf2(f1.x, f1.y); w.u[3] = packbf2(f1.z, f1.w);
        *(uint4*)((char*)wsK + (size_t)row * 256 + ((c * 16) ^ ((row & 7) << 4))) = w.q;
    } else {
        // V^T via LDS: block = one (h, tile).
        __shared__ __align__(8) unsigned short sV[HD * 68];  // [d][r], stride 68 bf16
        const int ntile = S >> 6;
        const int b = bid - nKblk;
        const int h = b / ntile;
        const int t = b - h * ntile;
        const float* vb = V + ((size_t)h * S + t * 64) * HD;
        {
            const int rp = tid >> 3;
            const int dc = tid & 7;
            const int r0 = rp * 2;
            const int d0 = dc * 16;
            const float* p0 = vb + (size_t)r0 * HD + d0;
            const float* p1 = p0 + HD;
            float4 a0 = *(const float4*)(p0 + 0),  a1 = *(const float4*)(p0 + 4);
            float4 a2 = *(const float4*)(p0 + 8),  a3 = *(const float4*)(p0 + 12);
            float4 b0 = *(const float4*)(p1 + 0),  b1 = *(const float4*)(p1 + 4);
            float4 b2 = *(const float4*)(p1 + 8),  b3 = *(const float4*)(p1 + 12);
            float av[16] = {a0.x,a0.y,a0.z,a0.w, a1.x,a1.y,a1.z,a1.w,
                            a2.x,a2.y,a2.z,a2.w, a3.x,a3.y,a3.z,a3.w};
            float bv[16] = {b0.x,b0.y,b0.z,b0.w, b1.x,b1.y,b1.z,b1.w,
                            b2.x,b2.y,b2.z,b2.w, b3.x,b3.y,b3.z,b3.w};
            #pragma unroll
            for (int i = 0; i < 16; ++i) {
                unsigned pr = packbf2(av[i], bv[i]);   // keys r0 (lo), r0+1 (hi)
                *(unsigned*)((char*)sV + ((size_t)(d0 + i) * 68 + r0) * 2) = pr;
            }
        }
        __syncthreads();
        const int d  = tid >> 1;
        const int jj = tid & 1;
        char* dstrow = (char*)wsVT + (((size_t)(h * ntile + t) * HD + d) * 128);
        const int dx = (d & 7) << 4;
        const unsigned short* srow = sV + (size_t)d * 68;
        #pragma unroll
        for (int u = 0; u < 4; ++u) {
            const int j  = jj * 4 + u;
            const int k0 = (j >> 2) * 32 + (j & 3) * 4;
            uint2 lo = *(const uint2*)(srow + k0);        // keys k0..k0+3
            uint2 hi = *(const uint2*)(srow + k0 + 16);   // keys k0+16..k0+19
            uint4 w = make_uint4(lo.x, lo.y, hi.x, hi.y);
            *(uint4*)(dstrow + ((j * 16) ^ dx)) = w;
        }
    }
}

// ---------------- main attention kernel ----------------
__global__ __launch_bounds__(256, 2) void fa_fwd(
    const float* __restrict__ Q,
    const unsigned short* __restrict__ wsK,
    const unsigned short* __restrict__ wsVT,
    const int* __restrict__ cu_seqlens, int n_cu,
    float* __restrict__ O,
    int S, int split_en,
    unsigned* __restrict__ cnt, float* __restrict__ part)
{
    __shared__ alignas(16) __hip_bfloat16 sK[2][BC * HD];    // 2 x 16KB
    __shared__ alignas(16) unsigned int   sVT[2][HD * 32];   // 2 x 16KB
    __shared__ int rank_sh;

    const int tid  = threadIdx.x;
    const int wave = tid >> 6;
    const int lane = tid & 63;
    const int quad = lane >> 4;
    const int l16  = lane & 15;
    const int kx   = (l16 & 7) << 4;        // read-side XOR (matches prepack)

    const int nqb = S / BR;
    const int h   = blockIdx.x & 7;
    int g = (int)(blockIdx.x >> 3);
    int qb, piece;
    if (split_en) {
        qb    = nqb - 1 - (g >> 1);   // heavy blocks dispatched first
        piece = g & 1;
    } else {
        piece = 0;
        if (nqb == 64) {              // R11 balanced pairing fallback
            if (g < 32) qb = (g >> 4) * 16 + (15 - (g & 15));
            else        qb = 32 + (((g - 32) >> 4) * 16) + (g & 15);
        } else qb = nqb - 1 - g;
    }
    const int q0    = qb * BR;
    const int qw    = q0 + wave * 16;
    const int qlane = qw + l16;     // the ONE query this lane owns

    // ---- block-uniform doc geometry ----
    int blk_ds = 0;
    for (int i = 0; i < n_cu; ++i) {
        int c = cu_seqlens[i];
        if (c <= q0) blk_ds = c;
    }
    const int k_begin = blk_ds & ~(BC - 1);
    const int n = (q0 + BR - 1 - k_begin) / BC + 1;

    const bool split = split_en && (n > MAXCHAIN);
    if (!split && piece) return;                  // idle twin
    const int it0 = (split && piece)  ? n / 2 : 0;
    const int it1 = (split && !piece) ? n / 2 : n;

    // ---- staging: 8x global_load_lds dwordx4 per thread ----
    const char* gkb = (const char*)wsK + (size_t)h * S * 256;
    const char* gvb = (const char*)wsVT + (size_t)h * (S >> 6) * 16384;
    const int lo = lane * 16;
    auto stage = [&](int kt, int buf) {
        const char* gk = gkb + (size_t)kt * 256 + wave * 4096 + lo;
        const char* gv = gvb + (size_t)(kt >> 6) * 16384 + wave * 4096 + lo;
        char* lk = (char*)&sK[buf][0] + wave * 4096;   // wave-uniform base
        char* lv = (char*)&sVT[buf][0] + wave * 4096;
        #pragma unroll
        for (int c = 0; c < 4; ++c) gll16(gk + c * 1024, lk + c * 1024);
        #pragma unroll
        for (int c = 0; c < 4; ++c) gll16(gv + c * 1024, lv + c * 1024);
    };

    stage(k_begin + it0 * BC, 0);   // issue ASAP; latency hides under prologue

    const size_t hoff = (size_t)h * S * HD;
    const float* Qh = Q + hoff;
    float*       Oh = O + hoff;

    // ---- per-lane doc start ----
    int ds_lane = 0;
    for (int i = 0; i < n_cu; ++i) {
        int c = cu_seqlens[i];
        if (c <= qlane) ds_lane = c;
    }

    // ---- Q fragments (B-operand: lane holds Q[qlane][ks*32+quad*8+j]) ----
    short8 aq[4];
    {
        const float* qp = Qh + (size_t)qlane * HD + quad * 8;
        #pragma unroll
        for (int ks = 0; ks < 4; ++ks) {
            float4 a0 = *(const float4*)(qp + ks * 32);
            float4 a1 = *(const float4*)(qp + ks * 32 + 4);
            short8 a;
            a[0] = bfs(a0.x); a[1] = bfs(a0.y); a[2] = bfs(a0.z); a[3] = bfs(a0.w);
            a[4] = bfs(a1.x); a[5] = bfs(a1.y); a[6] = bfs(a1.z); a[7] = bfs(a1.w);
            aq[ks] = a;
        }
    }

    // oacc[dt][r] = O[qlane][dt*16 + quad*4 + r]  (O^T layout)
    floatx4 oacc[8];
    #pragma unroll
    for (int dt = 0; dt < 8; ++dt) oacc[dt] = (floatx4){0.f, 0.f, 0.f, 0.f};
    float m_r = -1e30f, l_r = 0.f;

    const float sl = 0.08838834764831845f * 1.4426950408889634f;

    __syncthreads();    // drains stage vmcnt + all waves ready

    for (int it = it0; it < it1; ++it) {
        const int kt  = k_begin + it * BC;
        const int buf = (it - it0) & 1;

        if (it + 1 < it1) stage(k_begin + (it + 1) * BC, buf ^ 1);

        const char* kbase = (const char*)&sK[buf][0];
        const char* vbase = (const char*)&sVT[buf][0];

        // ---- S^T = K Q^T (skip fully-masked 16-key blocks) ----
        floatx4 sc[4];
        __builtin_amdgcn_s_setprio(1);
        #pragma unroll
        for (int ct = 0; ct < 4; ++ct) {
            if (kt + ct * 16 <= qw + 15) {       // wave-uniform
                floatx4 c = (floatx4){0.f, 0.f, 0.f, 0.f};
                #pragma unroll
                for (int ks = 0; ks < 4; ++ks) {
                    short8 a = *(const short8*)(kbase + (ct * 16 + l16) * 256
                                                + (((ks * 4 + quad) << 4) ^ kx));
                    c = __builtin_amdgcn_mfma_f32_16x16x32_bf16(a, aq[ks], c, 0, 0, 0);
                }
                sc[ct] = c;
            } else {
                sc[ct] = (floatx4){-1e30f, -1e30f, -1e30f, -1e30f};
            }
        }
        __builtin_amdgcn_s_setprio(0);

        // ---- mask + scale ----
        #pragma unroll
        for (int ct = 0; ct < 4; ++ct) {
            if (kt + ct * 16 <= qw + 15) {
                #pragma unroll
                for (int r = 0; r < 4; ++r) {
                    const int key = kt + ct * 16 + quad * 4 + r;
                    const bool valid = (key <= qlane) && (key >= ds_lane);
                    float s = sc[ct][r] * sl;
                    sc[ct][r] = valid ? s : -1e30f;
                }
            }
        }

        // ---- online softmax: in-lane tree + 2 shfl ----
        float mx0 = fmaxf(fmaxf(sc[0][0], sc[0][1]), fmaxf(sc[0][2], sc[0][3]));
        float mx1 = fmaxf(fmaxf(sc[1][0], sc[1][1]), fmaxf(sc[1][2], sc[1][3]));
        float mx2 = fmaxf(fmaxf(sc[2][0], sc[2][1]), fmaxf(sc[2][2], sc[2][3]));
        float mx3 = fmaxf(fmaxf(sc[3][0], sc[3][1]), fmaxf(sc[3][2], sc[3][3]));
        float mx  = fmaxf(fmaxf(mx0, mx1), fmaxf(mx2, mx3));
        mx = fmaxf(mx, __shfl_xor(mx, 16, 64));
        mx = fmaxf(mx, __shfl_xor(mx, 32, 64));

        const float mnew = fmaxf(m_r, mx);
        const float al   = exp2f(m_r - mnew);
        m_r = mnew;

        float s0 = 0.f, s1 = 0.f, s2 = 0.f, s3 = 0.f;
        #pragma unroll
        for (int ct = 0; ct < 4; ++ct) {
            float p0 = exp2f(sc[ct][0] - m_r);
            float p1 = exp2f(sc[ct][1] - m_r);
            float p2 = exp2f(sc[ct][2] - m_r);
            float p3 = exp2f(sc[ct][3] - m_r);
            sc[ct][0] = p0; sc[ct][1] = p1; sc[ct][2] = p2; sc[ct][3] = p3;
            s0 += p0; s1 += p1; s2 += p2; s3 += p3;
        }
        l_r = l_r * al + ((s0 + s1) + (s2 + s3));
        #pragma unroll
        for (int dt = 0; dt < 8; ++dt) {
            #pragma unroll
            for (int r = 0; r < 4; ++r)
                oacc[dt][r] *= al;
        }

        // ---- O^T += V^T P^T (P stays in registers) ----
        __builtin_amdgcn_s_setprio(1);
        #pragma unroll
        for (int ks = 0; ks < 2; ++ks) {
            if (kt + ks * 32 <= qw + 15) {       // wave-uniform
                union { unsigned u[4]; short8 s; } pu;   // B-frag = own p-values
                pu.u[0] = packbf2(sc[2*ks][0],   sc[2*ks][1]);
                pu.u[1] = packbf2(sc[2*ks][2],   sc[2*ks][3]);
                pu.u[2] = packbf2(sc[2*ks+1][0], sc[2*ks+1][1]);
                pu.u[3] = packbf2(sc[2*ks+1][2], sc[2*ks+1][3]);
                #pragma unroll
                for (int dt = 0; dt < 8; ++dt) {
                    union { uint4 q; short8 s; } cv;
                    cv.q = *(const uint4*)(vbase + (dt * 16 + l16) * 128
                                           + (((ks * 4 + quad) << 4) ^ kx));
                    oacc[dt] = __builtin_amdgcn_mfma_f32_16x16x32_bf16(cv.s, pu.s, oacc[dt], 0, 0, 0);
                }
            }
        }
        __builtin_amdgcn_s_setprio(0);

        __syncthreads();   // drains vmcnt (next-tile stage) + readers of buf
    }

    // ---- reduce l over quads ----
    l_r += __shfl_xor(l_r, 16, 64);
    l_r += __shfl_xor(l_r, 32, 64);

    if (!split) {
        const float inv = 1.0f / l_r;
        float* op = Oh + (size_t)qlane * HD + quad * 4;
        #pragma unroll
        for (int dt = 0; dt < 8; ++dt) {
            float4 st;
            st.x = oacc[dt][0] * inv;
            st.y = oacc[dt][1] * inv;
            st.z = oacc[dt][2] * inv;
            st.w = oacc[dt][3] * inv;
            *(float4*)(op + dt * 16) = st;
        }
        return;
    }

    // ---- split path: write partial (m, l, O_unnorm), last finisher merges ----
    const int slot = h * nqb + qb;
    float* pb = part + (size_t)slot * 16640 + piece * 8192;
    const int qlocal = wave * 16 + l16;
    {
        float* orow = pb + (size_t)qlocal * 128 + quad * 4;
        #pragma unroll
        for (int dt = 0; dt < 8; ++dt) {
            float4 st;
            st.x = oacc[dt][0]; st.y = oacc[dt][1];
            st.z = oacc[dt][2]; st.w = oacc[dt][3];
            *(float4*)(orow + dt * 16) = st;
        }
        float* mlb = part + (size_t)slot * 16640 + 16384;
        if (quad == 0) {
            mlb[piece * 128 + qlocal]      = m_r;
            mlb[piece * 128 + 64 + qlocal] = l_r;
        }
    }
    __threadfence();                 // release partials
    __syncthreads();
    if (tid == 0) rank_sh = (int)atomicAdd(&cnt[slot], 1u);
    __syncthreads();
    if (rank_sh != 1) return;        // first finisher: partner will merge

    __threadfence();                 // acquire partner's partials
    const float* O1  = part + (size_t)slot * 16640;
    const float* O2  = O1 + 8192;
    const float* mlb = O1 + 16384;
    #pragma unroll
    for (int kk = 0; kk < 8; ++kk) {
        const int fidx = tid + kk * 256;     // float4 index 0..2047
        const int row  = fidx >> 5;          // q_local
        const int c4   = fidx & 31;
        const float m1 = mlb[row],       l1 = mlb[64 + row];
        const float m2 = mlb[128 + row], l2 = mlb[192 + row];
        const float M  = fmaxf(m1, m2);
        const float w1 = exp2f(m1 - M), w2 = exp2f(m2 - M);
        const float inv = 1.0f / (w1 * l1 + w2 * l2);
        float4 a = *(const float4*)(O1 + (size_t)fidx * 4);
        float4 b = *(const float4*)(O2 + (size_t)fidx * 4);
        float4 o;
        o.x = (w1 * a.x + w2 * b.x) * inv;
        o.y = (w1 * a.y + w2 * b.y) * inv;
        o.z = (w1 * a.z + w2 * b.z) * inv;
        o.w = (w1 * a.w + w2 * b.w) * inv;
        *(float4*)(Oh + (size_t)(q0 + row) * HD + c4 * 4) = o;
    }
}

extern "C" void kernel_launch(void* const* d_in, const int* in_sizes, int n_in,
                              void* d_out, int out_size, void* d_ws, size_t ws_size,
                              hipStream_t stream) {
    const float* q = (const float*)d_in[0];
    const float* k = (const float*)d_in[1];
    const float* v = (const float*)d_in[2];
    const int* cu = (const int*)d_in[3];
    const int n_cu = in_sizes[3];
    const int H = 8;
    const int S = in_sizes[0] / (H * HD);   // B=1
    float* out = (float*)d_out;

    const int nqb = S / BR;
    unsigned short* wsK  = (unsigned short*)d_ws;                 // H*S*256 B
    unsigned short* wsVT = wsK + (size_t)H * S * HD;              // H*S*256 B
    const size_t kvbytes = (size_t)2 * H * S * HD * 2;
    const size_t cntbytes = ((size_t)H * nqb * 4 + 255) & ~(size_t)255;
    unsigned* cnt = (unsigned*)((char*)d_ws + kvbytes);
    float* part = (float*)((char*)d_ws + kvbytes + cntbytes);
    const size_t need = kvbytes + cntbytes + (size_t)H * nqb * 66560;
    const int split_en = (ws_size >= need) ? 1 : 0;

    if (split_en) hipMemsetAsync(cnt, 0, (size_t)H * nqb * 4, stream);

    const int nKblk = (H * S) / 16;          // 2048
    const int nVblk = H * (S >> 6);          // 512
    prepack<<<dim3(nKblk + nVblk), dim3(256), 0, stream>>>(k, v, wsK, wsVT, S);

    dim3 grid(H * nqb * (split_en ? 2 : 1));
    dim3 block(256);
    fa_fwd<<<grid, block, 0, stream>>>(q, wsK, wsVT, cu, n_cu, out, S,
                                       split_en, cnt, part);
}

// Round 5
// 143.941 us; speedup vs baseline: 1.7023x; 1.7023x over previous
//
#include <hip/hip_runtime.h>
#include <hip/hip_bf16.h>

// Flash-attention fwd, block-causal packed docs. fp32 HBM, bf16 MFMA.
// B=1, H=8, D=128. R14 = R11 kernel (BR=64, 4 waves, 2 blocks/CU; proven
// 46.4us) + FENCE-FREE split-K:
//  - R13 lesson (counters): per-block __threadfence on gfx950 = buffer_wbl2
//    (full L2 writeback) / buffer_inv (full L2 invalidate) -> 512 L2 flushes,
//    partials forced to HBM (+16.6MB WRITE, +8.3MB FETCH), co-resident
//    blocks' cached K/V evicted, 46->157us. NEVER per-block device fences.
//  - R14: split q-blocks with n>8 tiles into two pieces ([0,n/2) all-full,
//    [n/2,n) diagonal); pieces write partial (m,l,O_unnorm) with PLAIN
//    stores; a SECOND kernel merges. Kernel boundary = one global
//    release/acquire (runtime barrier packet), zero in-kernel fences/atomics.
//  - Longest serial chain 16 -> 8 tiles; grid 1024, heavy half (both pieces
//    of qb>=32) = first 512 blockIdx -> all co-resident at t=0.
// Keeps: swapped-operand QK^T (lane owns one query), P-in-registers PV,
// prepacked bf16 K / key-permuted V^T in d_ws (XOR-swizzled, gll16
// direct-to-LDS staging: linear dest + pre-swizzled src + swizzled read),
// double buffer, 1 barrier/tile, setprio on MFMA clusters.

#define HD 128
#define BR 64
#define BC 64
#define MAXCHAIN 8

typedef __attribute__((ext_vector_type(8))) short short8;
typedef __attribute__((ext_vector_type(4))) float floatx4;

__device__ inline unsigned packbf2(float lo, float hi) {
    __hip_bfloat162 h2 = __float22bfloat162_rn(make_float2(lo, hi));
    return *reinterpret_cast<unsigned*>(&h2);   // low16 = lo, high16 = hi
}
__device__ inline short bfs(float f) {
    __hip_bfloat16 b = __float2bfloat16(f);
    return *reinterpret_cast<short*>(&b);
}

__device__ inline void gll16(const void* g, void* l) {
    __builtin_amdgcn_global_load_lds(
        (const __attribute__((address_space(1))) unsigned int*)g,
        (__attribute__((address_space(3))) unsigned int*)l, 16, 0, 0);
}

// ---------------- prepack: fp32 -> bf16, swizzled (as R12) ----------------
__global__ __launch_bounds__(256) void prepack(
    const float* __restrict__ K, const float* __restrict__ V,
    unsigned short* __restrict__ wsK, unsigned short* __restrict__ wsVT,
    int S)
{
    const int tid = threadIdx.x;
    const int nKblk = (8 * S) / 16;           // H*S*16 chunks / 256
    const int bid = blockIdx.x;
    if (bid < nKblk) {
        // K: one 16B output chunk (8 bf16 <- 8 fp32) per thread, coalesced.
        const int cid = bid * 256 + tid;
        const int row = cid >> 4;              // global row (h*S + r)
        const int c   = cid & 15;
        const float* src = K + (size_t)row * HD + c * 8;
        float4 f0 = *(const float4*)src;
        float4 f1 = *(const float4*)(src + 4);
        union { uint4 q; unsigned u[4]; } w;
        w.u[0] = packbf2(f0.x, f0.y); w.u[1] = packbf2(f0.z, f0.w);
        w.u[2] = packbf2(f1.x, f1.y); w.u[3] = packbf2(f1.z, f1.w);
        *(uint4*)((char*)wsK + (size_t)row * 256 + ((c * 16) ^ ((row & 7) << 4))) = w.q;
    } else {
        // V^T via LDS: block = one (h, tile).
        __shared__ __align__(8) unsigned short sV[HD * 68];  // [d][r], stride 68 bf16
        const int ntile = S >> 6;
        const int b = bid - nKblk;
        const int h = b / ntile;
        const int t = b - h * ntile;
        const float* vb = V + ((size_t)h * S + t * 64) * HD;
        {
            const int rp = tid >> 3;
            const int dc = tid & 7;
            const int r0 = rp * 2;
            const int d0 = dc * 16;
            const float* p0 = vb + (size_t)r0 * HD + d0;
            const float* p1 = p0 + HD;
            float4 a0 = *(const float4*)(p0 + 0),  a1 = *(const float4*)(p0 + 4);
            float4 a2 = *(const float4*)(p0 + 8),  a3 = *(const float4*)(p0 + 12);
            float4 b0 = *(const float4*)(p1 + 0),  b1 = *(const float4*)(p1 + 4);
            float4 b2 = *(const float4*)(p1 + 8),  b3 = *(const float4*)(p1 + 12);
            float av[16] = {a0.x,a0.y,a0.z,a0.w, a1.x,a1.y,a1.z,a1.w,
                            a2.x,a2.y,a2.z,a2.w, a3.x,a3.y,a3.z,a3.w};
            float bv[16] = {b0.x,b0.y,b0.z,b0.w, b1.x,b1.y,b1.z,b1.w,
                            b2.x,b2.y,b2.z,b2.w, b3.x,b3.y,b3.z,b3.w};
            #pragma unroll
            for (int i = 0; i < 16; ++i) {
                unsigned pr = packbf2(av[i], bv[i]);   // keys r0 (lo), r0+1 (hi)
                *(unsigned*)((char*)sV + ((size_t)(d0 + i) * 68 + r0) * 2) = pr;
            }
        }
        __syncthreads();
        const int d  = tid >> 1;
        const int jj = tid & 1;
        char* dstrow = (char*)wsVT + (((size_t)(h * ntile + t) * HD + d) * 128);
        const int dx = (d & 7) << 4;
        const unsigned short* srow = sV + (size_t)d * 68;
        #pragma unroll
        for (int u = 0; u < 4; ++u) {
            const int j  = jj * 4 + u;
            const int k0 = (j >> 2) * 32 + (j & 3) * 4;
            uint2 lo = *(const uint2*)(srow + k0);        // keys k0..k0+3
            uint2 hi = *(const uint2*)(srow + k0 + 16);   // keys k0+16..k0+19
            uint4 w = make_uint4(lo.x, lo.y, hi.x, hi.y);
            *(uint4*)(dstrow + ((j * 16) ^ dx)) = w;
        }
    }
}

// ---------------- main attention kernel (pieces) ----------------
__global__ __launch_bounds__(256, 2) void fa_fwd(
    const float* __restrict__ Q,
    const unsigned short* __restrict__ wsK,
    const unsigned short* __restrict__ wsVT,
    const int* __restrict__ cu_seqlens, int n_cu,
    float* __restrict__ O,
    int S, int split_en,
    float* __restrict__ part)
{
    __shared__ alignas(16) __hip_bfloat16 sK[2][BC * HD];    // 2 x 16KB
    __shared__ alignas(16) unsigned int   sVT[2][HD * 32];   // 2 x 16KB

    const int tid  = threadIdx.x;
    const int wave = tid >> 6;
    const int lane = tid & 63;
    const int quad = lane >> 4;
    const int l16  = lane & 15;
    const int kx   = (l16 & 7) << 4;        // read-side XOR (matches prepack)

    const int nqb = S / BR;
    const int h   = blockIdx.x & 7;
    int g = (int)(blockIdx.x >> 3);
    int qb, piece;
    if (split_en) {
        qb    = nqb - 1 - (g >> 1);   // heavy blocks dispatched first
        piece = g & 1;
    } else {
        piece = 0;
        if (nqb == 64) {              // R11 balanced pairing fallback
            if (g < 32) qb = (g >> 4) * 16 + (15 - (g & 15));
            else        qb = 32 + (((g - 32) >> 4) * 16) + (g & 15);
        } else qb = nqb - 1 - g;
    }
    const int q0    = qb * BR;
    const int qw    = q0 + wave * 16;
    const int qlane = qw + l16;     // the ONE query this lane owns

    // ---- block-uniform doc geometry ----
    int blk_ds = 0;
    for (int i = 0; i < n_cu; ++i) {
        int c = cu_seqlens[i];
        if (c <= q0) blk_ds = c;
    }
    const int k_begin = blk_ds & ~(BC - 1);
    const int n = (q0 + BR - 1 - k_begin) / BC + 1;

    const bool split = split_en && (n > MAXCHAIN);
    if (!split && piece) return;                  // idle twin
    const int it0 = (split && piece)  ? n / 2 : 0;
    const int it1 = (split && !piece) ? n / 2 : n;

    // ---- staging: 8x global_load_lds dwordx4 per thread ----
    const char* gkb = (const char*)wsK + (size_t)h * S * 256;
    const char* gvb = (const char*)wsVT + (size_t)h * (S >> 6) * 16384;
    const int lo = lane * 16;
    auto stage = [&](int kt, int buf) {
        const char* gk = gkb + (size_t)kt * 256 + wave * 4096 + lo;
        const char* gv = gvb + (size_t)(kt >> 6) * 16384 + wave * 4096 + lo;
        char* lk = (char*)&sK[buf][0] + wave * 4096;   // wave-uniform base
        char* lv = (char*)&sVT[buf][0] + wave * 4096;
        #pragma unroll
        for (int c = 0; c < 4; ++c) gll16(gk + c * 1024, lk + c * 1024);
        #pragma unroll
        for (int c = 0; c < 4; ++c) gll16(gv + c * 1024, lv + c * 1024);
    };

    stage(k_begin + it0 * BC, 0);   // issue ASAP; latency hides under prologue

    const size_t hoff = (size_t)h * S * HD;
    const float* Qh = Q + hoff;
    float*       Oh = O + hoff;

    // ---- per-lane doc start ----
    int ds_lane = 0;
    for (int i = 0; i < n_cu; ++i) {
        int c = cu_seqlens[i];
        if (c <= qlane) ds_lane = c;
    }

    // ---- Q fragments (B-operand: lane holds Q[qlane][ks*32+quad*8+j]) ----
    short8 aq[4];
    {
        const float* qp = Qh + (size_t)qlane * HD + quad * 8;
        #pragma unroll
        for (int ks = 0; ks < 4; ++ks) {
            float4 a0 = *(const float4*)(qp + ks * 32);
            float4 a1 = *(const float4*)(qp + ks * 32 + 4);
            short8 a;
            a[0] = bfs(a0.x); a[1] = bfs(a0.y); a[2] = bfs(a0.z); a[3] = bfs(a0.w);
            a[4] = bfs(a1.x); a[5] = bfs(a1.y); a[6] = bfs(a1.z); a[7] = bfs(a1.w);
            aq[ks] = a;
        }
    }

    // oacc[dt][r] = O[qlane][dt*16 + quad*4 + r]  (O^T layout)
    floatx4 oacc[8];
    #pragma unroll
    for (int dt = 0; dt < 8; ++dt) oacc[dt] = (floatx4){0.f, 0.f, 0.f, 0.f};
    float m_r = -1e30f, l_r = 0.f;

    const float sl = 0.08838834764831845f * 1.4426950408889634f;

    __syncthreads();    // drains stage vmcnt + all waves ready

    for (int it = it0; it < it1; ++it) {
        const int kt  = k_begin + it * BC;
        const int buf = (it - it0) & 1;

        if (it + 1 < it1) stage(k_begin + (it + 1) * BC, buf ^ 1);

        const char* kbase = (const char*)&sK[buf][0];
        const char* vbase = (const char*)&sVT[buf][0];

        // ---- S^T = K Q^T (skip fully-masked 16-key blocks) ----
        floatx4 sc[4];
        __builtin_amdgcn_s_setprio(1);
        #pragma unroll
        for (int ct = 0; ct < 4; ++ct) {
            if (kt + ct * 16 <= qw + 15) {       // wave-uniform
                floatx4 c = (floatx4){0.f, 0.f, 0.f, 0.f};
                #pragma unroll
                for (int ks = 0; ks < 4; ++ks) {
                    short8 a = *(const short8*)(kbase + (ct * 16 + l16) * 256
                                                + (((ks * 4 + quad) << 4) ^ kx));
                    c = __builtin_amdgcn_mfma_f32_16x16x32_bf16(a, aq[ks], c, 0, 0, 0);
                }
                sc[ct] = c;
            } else {
                sc[ct] = (floatx4){-1e30f, -1e30f, -1e30f, -1e30f};
            }
        }
        __builtin_amdgcn_s_setprio(0);

        // ---- mask + scale ----
        #pragma unroll
        for (int ct = 0; ct < 4; ++ct) {
            if (kt + ct * 16 <= qw + 15) {
                #pragma unroll
                for (int r = 0; r < 4; ++r) {
                    const int key = kt + ct * 16 + quad * 4 + r;
                    const bool valid = (key <= qlane) && (key >= ds_lane);
                    float s = sc[ct][r] * sl;
                    sc[ct][r] = valid ? s : -1e30f;
                }
            }
        }

        // ---- online softmax: in-lane tree + 2 shfl ----
        float mx0 = fmaxf(fmaxf(sc[0][0], sc[0][1]), fmaxf(sc[0][2], sc[0][3]));
        float mx1 = fmaxf(fmaxf(sc[1][0], sc[1][1]), fmaxf(sc[1][2], sc[1][3]));
        float mx2 = fmaxf(fmaxf(sc[2][0], sc[2][1]), fmaxf(sc[2][2], sc[2][3]));
        float mx3 = fmaxf(fmaxf(sc[3][0], sc[3][1]), fmaxf(sc[3][2], sc[3][3]));
        float mx  = fmaxf(fmaxf(mx0, mx1), fmaxf(mx2, mx3));
        mx = fmaxf(mx, __shfl_xor(mx, 16, 64));
        mx = fmaxf(mx, __shfl_xor(mx, 32, 64));

        const float mnew = fmaxf(m_r, mx);
        const float al   = exp2f(m_r - mnew);
        m_r = mnew;

        float s0 = 0.f, s1 = 0.f, s2 = 0.f, s3 = 0.f;
        #pragma unroll
        for (int ct = 0; ct < 4; ++ct) {
            float p0 = exp2f(sc[ct][0] - m_r);
            float p1 = exp2f(sc[ct][1] - m_r);
            float p2 = exp2f(sc[ct][2] - m_r);
            float p3 = exp2f(sc[ct][3] - m_r);
            sc[ct][0] = p0; sc[ct][1] = p1; sc[ct][2] = p2; sc[ct][3] = p3;
            s0 += p0; s1 += p1; s2 += p2; s3 += p3;
        }
        l_r = l_r * al + ((s0 + s1) + (s2 + s3));
        #pragma unroll
        for (int dt = 0; dt < 8; ++dt) {
            #pragma unroll
            for (int r = 0; r < 4; ++r)
                oacc[dt][r] *= al;
        }

        // ---- O^T += V^T P^T (P stays in registers) ----
        __builtin_amdgcn_s_setprio(1);
        #pragma unroll
        for (int ks = 0; ks < 2; ++ks) {
            if (kt + ks * 32 <= qw + 15) {       // wave-uniform
                union { unsigned u[4]; short8 s; } pu;   // B-frag = own p-values
                pu.u[0] = packbf2(sc[2*ks][0],   sc[2*ks][1]);
                pu.u[1] = packbf2(sc[2*ks][2],   sc[2*ks][3]);
                pu.u[2] = packbf2(sc[2*ks+1][0], sc[2*ks+1][1]);
                pu.u[3] = packbf2(sc[2*ks+1][2], sc[2*ks+1][3]);
                #pragma unroll
                for (int dt = 0; dt < 8; ++dt) {
                    union { uint4 q; short8 s; } cv;
                    cv.q = *(const uint4*)(vbase + (dt * 16 + l16) * 128
                                           + (((ks * 4 + quad) << 4) ^ kx));
                    oacc[dt] = __builtin_amdgcn_mfma_f32_16x16x32_bf16(cv.s, pu.s, oacc[dt], 0, 0, 0);
                }
            }
        }
        __builtin_amdgcn_s_setprio(0);

        __syncthreads();   // drains vmcnt (next-tile stage) + readers of buf
    }

    // ---- reduce l over quads ----
    l_r += __shfl_xor(l_r, 16, 64);
    l_r += __shfl_xor(l_r, 32, 64);

    if (!split) {
        const float inv = 1.0f / l_r;
        float* op = Oh + (size_t)qlane * HD + quad * 4;
        #pragma unroll
        for (int dt = 0; dt < 8; ++dt) {
            float4 st;
            st.x = oacc[dt][0] * inv;
            st.y = oacc[dt][1] * inv;
            st.z = oacc[dt][2] * inv;
            st.w = oacc[dt][3] * inv;
            *(float4*)(op + dt * 16) = st;
        }
        return;
    }

    // ---- split path: write partial (m, l, O_unnorm); merge is kernel 2 ----
    const int slot = h * nqb + qb;
    float* pb = part + (size_t)slot * 16640 + piece * 8192;
    const int qlocal = wave * 16 + l16;
    float* orow = pb + (size_t)qlocal * 128 + quad * 4;
    #pragma unroll
    for (int dt = 0; dt < 8; ++dt) {
        float4 st;
        st.x = oacc[dt][0]; st.y = oacc[dt][1];
        st.z = oacc[dt][2]; st.w = oacc[dt][3];
        *(float4*)(orow + dt * 16) = st;
    }
    float* mlb = part + (size_t)slot * 16640 + 16384;
    if (quad == 0) {
        mlb[piece * 128 + qlocal]      = m_r;
        mlb[piece * 128 + 64 + qlocal] = l_r;
    }
}

// ---------------- merge kernel (fence-free: kernel boundary syncs) ----------
__global__ __launch_bounds__(256) void fa_merge(
    const int* __restrict__ cu_seqlens, int n_cu,
    const float* __restrict__ part,
    float* __restrict__ O, int S)
{
    const int nqb = S / BR;
    const int bid = blockIdx.x;
    const int h   = bid / nqb;
    const int qb  = bid - h * nqb;
    const int q0  = qb * BR;

    int blk_ds = 0;
    for (int i = 0; i < n_cu; ++i) {
        int c = cu_seqlens[i];
        if (c <= q0) blk_ds = c;
    }
    const int k_begin = blk_ds & ~(BC - 1);
    const int n = (q0 + BR - 1 - k_begin) / BC + 1;
    if (n <= MAXCHAIN) return;               // not split; fa_fwd wrote O

    const int tid = threadIdx.x;
    const float* O1  = part + (size_t)bid * 16640;
    const float* O2  = O1 + 8192;
    const float* mlb = O1 + 16384;
    float* Oh = O + (size_t)h * S * HD;
    #pragma unroll
    for (int kk = 0; kk < 8; ++kk) {
        const int fidx = tid + kk * 256;     // float4 index 0..2047
        const int row  = fidx >> 5;          // q_local
        const int c4   = fidx & 31;
        const float m1 = mlb[row],       l1 = mlb[64 + row];
        const float m2 = mlb[128 + row], l2 = mlb[192 + row];
        const float M  = fmaxf(m1, m2);
        const float w1 = exp2f(m1 - M), w2 = exp2f(m2 - M);
        const float inv = 1.0f / (w1 * l1 + w2 * l2);
        float4 a = *(const float4*)(O1 + (size_t)fidx * 4);
        float4 b = *(const float4*)(O2 + (size_t)fidx * 4);
        float4 o;
        o.x = (w1 * a.x + w2 * b.x) * inv;
        o.y = (w1 * a.y + w2 * b.y) * inv;
        o.z = (w1 * a.z + w2 * b.z) * inv;
        o.w = (w1 * a.w + w2 * b.w) * inv;
        *(float4*)(Oh + (size_t)(q0 + row) * HD + c4 * 4) = o;
    }
}

extern "C" void kernel_launch(void* const* d_in, const int* in_sizes, int n_in,
                              void* d_out, int out_size, void* d_ws, size_t ws_size,
                              hipStream_t stream) {
    const float* q = (const float*)d_in[0];
    const float* k = (const float*)d_in[1];
    const float* v = (const float*)d_in[2];
    const int* cu = (const int*)d_in[3];
    const int n_cu = in_sizes[3];
    const int H = 8;
    const int S = in_sizes[0] / (H * HD);   // B=1
    float* out = (float*)d_out;

    const int nqb = S / BR;
    unsigned short* wsK  = (unsigned short*)d_ws;                 // H*S*256 B
    unsigned short* wsVT = wsK + (size_t)H * S * HD;              // H*S*256 B
    const size_t kvbytes = (size_t)2 * H * S * HD * 2;
    float* part = (float*)((char*)d_ws + kvbytes);
    const size_t need = kvbytes + (size_t)H * nqb * 66560;
    const int split_en = (ws_size >= need) ? 1 : 0;

    const int nKblk = (H * S) / 16;          // 2048
    const int nVblk = H * (S >> 6);          // 512
    prepack<<<dim3(nKblk + nVblk), dim3(256), 0, stream>>>(k, v, wsK, wsVT, S);

    dim3 grid(H * nqb * (split_en ? 2 : 1));
    dim3 block(256);
    fa_fwd<<<grid, block, 0, stream>>>(q, wsK, wsVT, cu, n_cu, out, S,
                                       split_en, part);
    if (split_en)
        fa_merge<<<dim3(H * nqb), dim3(256), 0, stream>>>(cu, n_cu, part, out, S);
}

// Round 6
// 135.412 us; speedup vs baseline: 1.8095x; 1.0630x over previous
//
#include <hip/hip_runtime.h>
#include <hip/hip_bf16.h>

// Flash-attention fwd, block-causal packed docs. fp32 HBM, bf16 MFMA.
// B=1, H=8, D=128. R15: 8-wave blocks with INTRA-BLOCK KEY-SPLIT.
//  - R14 falsified chain-length theory (16->8 tiles, same 47us at fixed
//    2 waves/SIMD). All pipe utils <25% & all throughput floors ~12-20us
//    => dependency-stall bound, under-filled SIMDs. Lever = waves/SIMD.
//  - R15: 512-thr blocks, waves 0-3 process keys [kt,kt+32), waves 4-7
//    [kt+32,kt+64) of the same tile. Same 64KB LDS => 2 blocks/CU x 8
//    waves = 16 waves/CU = 4 waves/SIMD (was 2), per-wave tile chain
//    HALVED (16 ds_read_b128 + 16 MFMA + 8-val softmax).
//  - group partials (m,l,O^T) merged ONCE at end via LDS (no HBM partials,
//    no fences - R13 lesson). `live` guard kills exp2(−1e30−(−1e30))=1
//    for queries whose key-half never has a valid key.
//  - same-n pairing: qb=g identity => blocks g,g+256 (same CU by R9 model)
//    have EQUAL ntiles; critical (16,16) CU keeps 4 waves/SIMD for its
//    whole life (vs (16,1): 15 tiles at half fill).
//  - prepack: V-blocks first (long blocks first, shorter tail).
// Keeps: swapped-operand QK^T (lane owns one query), P-in-registers PV,
// prepacked bf16 K / key-permuted V^T in d_ws (XOR-swizzled, gll16
// direct-to-LDS staging: linear dest + pre-swizzled src + swizzled read),
// double buffer, 1 barrier/tile, setprio on MFMA clusters.

#define HD 128
#define BR 64
#define BC 64

typedef __attribute__((ext_vector_type(8))) short short8;
typedef __attribute__((ext_vector_type(4))) float floatx4;

__device__ inline unsigned packbf2(float lo, float hi) {
    __hip_bfloat162 h2 = __float22bfloat162_rn(make_float2(lo, hi));
    return *reinterpret_cast<unsigned*>(&h2);   // low16 = lo, high16 = hi
}
__device__ inline short bfs(float f) {
    __hip_bfloat16 b = __float2bfloat16(f);
    return *reinterpret_cast<short*>(&b);
}

__device__ inline void gll16(const void* g, void* l) {
    __builtin_amdgcn_global_load_lds(
        (const __attribute__((address_space(1))) unsigned int*)g,
        (__attribute__((address_space(3))) unsigned int*)l, 16, 0, 0);
}

// ---------------- prepack: fp32 -> bf16, swizzled (V blocks first) --------
__global__ __launch_bounds__(256) void prepack(
    const float* __restrict__ K, const float* __restrict__ V,
    unsigned short* __restrict__ wsK, unsigned short* __restrict__ wsVT,
    int S)
{
    const int tid = threadIdx.x;
    const int nVblk = 8 * (S >> 6);
    const int bid = blockIdx.x;
    if (bid < nVblk) {
        // V^T via LDS: block = one (h, tile).
        __shared__ __align__(8) unsigned short sV[HD * 68];  // [d][r], stride 68 bf16
        const int ntile = S >> 6;
        const int h = bid / ntile;
        const int t = bid - h * ntile;
        const float* vb = V + ((size_t)h * S + t * 64) * HD;
        {
            const int rp = tid >> 3;
            const int dc = tid & 7;
            const int r0 = rp * 2;
            const int d0 = dc * 16;
            const float* p0 = vb + (size_t)r0 * HD + d0;
            const float* p1 = p0 + HD;
            float4 a0 = *(const float4*)(p0 + 0),  a1 = *(const float4*)(p0 + 4);
            float4 a2 = *(const float4*)(p0 + 8),  a3 = *(const float4*)(p0 + 12);
            float4 b0 = *(const float4*)(p1 + 0),  b1 = *(const float4*)(p1 + 4);
            float4 b2 = *(const float4*)(p1 + 8),  b3 = *(const float4*)(p1 + 12);
            float av[16] = {a0.x,a0.y,a0.z,a0.w, a1.x,a1.y,a1.z,a1.w,
                            a2.x,a2.y,a2.z,a2.w, a3.x,a3.y,a3.z,a3.w};
            float bv[16] = {b0.x,b0.y,b0.z,b0.w, b1.x,b1.y,b1.z,b1.w,
                            b2.x,b2.y,b2.z,b2.w, b3.x,b3.y,b3.z,b3.w};
            #pragma unroll
            for (int i = 0; i < 16; ++i) {
                unsigned pr = packbf2(av[i], bv[i]);   // keys r0 (lo), r0+1 (hi)
                *(unsigned*)((char*)sV + ((size_t)(d0 + i) * 68 + r0) * 2) = pr;
            }
        }
        __syncthreads();
        const int d  = tid >> 1;
        const int jj = tid & 1;
        char* dstrow = (char*)wsVT + (((size_t)(h * ntile + t) * HD + d) * 128);
        const int dx = (d & 7) << 4;
        const unsigned short* srow = sV + (size_t)d * 68;
        #pragma unroll
        for (int u = 0; u < 4; ++u) {
            const int j  = jj * 4 + u;
            const int k0 = (j >> 2) * 32 + (j & 3) * 4;
            uint2 lo = *(const uint2*)(srow + k0);        // keys k0..k0+3
            uint2 hi = *(const uint2*)(srow + k0 + 16);   // keys k0+16..k0+19
            uint4 w = make_uint4(lo.x, lo.y, hi.x, hi.y);
            *(uint4*)(dstrow + ((j * 16) ^ dx)) = w;
        }
    } else {
        // K: one 16B output chunk (8 bf16 <- 8 fp32) per thread, coalesced.
        const int cid = (bid - nVblk) * 256 + tid;
        const int row = cid >> 4;              // global row (h*S + r)
        const int c   = cid & 15;
        const float* src = K + (size_t)row * HD + c * 8;
        float4 f0 = *(const float4*)src;
        float4 f1 = *(const float4*)(src + 4);
        union { uint4 q; unsigned u[4]; } w;
        w.u[0] = packbf2(f0.x, f0.y); w.u[1] = packbf2(f0.z, f0.w);
        w.u[2] = packbf2(f1.x, f1.y); w.u[3] = packbf2(f1.z, f1.w);
        *(uint4*)((char*)wsK + (size_t)row * 256 + ((c * 16) ^ ((row & 7) << 4))) = w.q;
    }
}

// ---------------- main attention kernel ----------------
__global__ __launch_bounds__(512, 4) void fa_fwd(
    const float* __restrict__ Q,
    const unsigned short* __restrict__ wsK,
    const unsigned short* __restrict__ wsVT,
    const int* __restrict__ cu_seqlens, int n_cu,
    float* __restrict__ O,
    int S)
{
    __shared__ alignas(16) __hip_bfloat16 sK[2][BC * HD];    // 2 x 16KB
    __shared__ alignas(16) unsigned int   sVT[2][HD * 32];   // 2 x 16KB

    const int tid  = threadIdx.x;
    const int wave = tid >> 6;
    const int gp   = wave >> 2;             // key-half group 0/1
    const int wsub = wave & 3;              // query sub-block 0..3
    const int lane = tid & 63;
    const int quad = lane >> 4;
    const int l16  = lane & 15;
    const int kx   = (l16 & 7) << 4;        // read-side XOR (matches prepack)

    const int nqb = S / BR;
    const int h   = blockIdx.x & 7;
    const int g   = (int)(blockIdx.x >> 3);
    // same-n pairing: identity. CU model (b%8 xcd,(b>>3)%32) pairs blocks
    // g and g+32 (same h) -> qbs g,g+32 have equal ntiles when nqb==64.
    const int qb = (nqb == 64) ? g : (nqb - 1 - g);
    const int q0    = qb * BR;
    const int qw    = q0 + wsub * 16;
    const int qlane = qw + l16;     // the ONE query this lane owns

    // ---- block-uniform doc geometry ----
    int blk_ds = 0;
    for (int i = 0; i < n_cu; ++i) {
        int c = cu_seqlens[i];
        if (c <= q0) blk_ds = c;
    }
    const int k_begin = blk_ds & ~(BC - 1);
    const int ntiles  = (q0 + BR - 1 - k_begin) / BC + 1;

    // ---- staging: 4x global_load_lds dwordx4 per thread (8 waves) ----
    // waves 0-3 stage sK (4KB each), waves 4-7 stage sVT (4KB each).
    const char* gkb = (const char*)wsK + (size_t)h * S * 256;
    const char* gvb = (const char*)wsVT + (size_t)h * (S >> 6) * 16384;
    const int wofs = (wave & 3) * 4096;
    const int lo = wofs + lane * 16;
    auto stage = [&](int kt, int buf) {
        if (gp == 0) {
            const char* gk = gkb + (size_t)kt * 256 + lo;
            char* lk = (char*)&sK[buf][0] + wofs;          // wave-uniform base
            #pragma unroll
            for (int c = 0; c < 4; ++c) gll16(gk + c * 1024, lk + c * 1024);
        } else {
            const char* gv = gvb + (size_t)(kt >> 6) * 16384 + lo;
            char* lv = (char*)&sVT[buf][0] + wofs;
            #pragma unroll
            for (int c = 0; c < 4; ++c) gll16(gv + c * 1024, lv + c * 1024);
        }
    };

    stage(k_begin, 0);   // issue ASAP; latency hides under prologue

    const size_t hoff = (size_t)h * S * HD;
    const float* Qh = Q + hoff;
    float*       Oh = O + hoff;

    // ---- per-lane doc start ----
    int ds_lane = 0;
    for (int i = 0; i < n_cu; ++i) {
        int c = cu_seqlens[i];
        if (c <= qlane) ds_lane = c;
    }

    // ---- Q fragments (B-operand: lane holds Q[qlane][ks*32+quad*8+j]) ----
    short8 aq[4];
    {
        const float* qp = Qh + (size_t)qlane * HD + quad * 8;
        #pragma unroll
        for (int ks = 0; ks < 4; ++ks) {
            float4 a0 = *(const float4*)(qp + ks * 32);
            float4 a1 = *(const float4*)(qp + ks * 32 + 4);
            short8 a;
            a[0] = bfs(a0.x); a[1] = bfs(a0.y); a[2] = bfs(a0.z); a[3] = bfs(a0.w);
            a[4] = bfs(a1.x); a[5] = bfs(a1.y); a[6] = bfs(a1.z); a[7] = bfs(a1.w);
            aq[ks] = a;
        }
    }

    // oacc[dt][r] = O^T partial for THIS key-half: d=dt*16+quad*4+r, q=qlane
    floatx4 oacc[8];
    #pragma unroll
    for (int dt = 0; dt < 8; ++dt) oacc[dt] = (floatx4){0.f, 0.f, 0.f, 0.f};
    float m_r = -1e30f, l_r = 0.f;

    const float sl = 0.08838834764831845f * 1.4426950408889634f;

    __syncthreads();    // drains stage vmcnt + all waves ready

    for (int it = 0; it < ntiles; ++it) {
        const int kt  = k_begin + it * BC;
        const int buf = it & 1;

        if (it + 1 < ntiles) stage(kt + BC, buf ^ 1);

        if (kt + gp * 32 <= qw + 15) {       // wave-uniform key-half active
            const char* kbase = (const char*)&sK[buf][0];
            const char* vbase = (const char*)&sVT[buf][0];

            // ---- S^T = K Q^T over this wave's 32 keys (2 ct blocks) ----
            floatx4 sc[2];
            __builtin_amdgcn_s_setprio(1);
            #pragma unroll
            for (int ctl = 0; ctl < 2; ++ctl) {
                const int ct = 2 * gp + ctl;
                if (kt + ct * 16 <= qw + 15) {   // wave-uniform
                    floatx4 c = (floatx4){0.f, 0.f, 0.f, 0.f};
                    #pragma unroll
                    for (int ks = 0; ks < 4; ++ks) {
                        short8 a = *(const short8*)(kbase + (ct * 16 + l16) * 256
                                                    + (((ks * 4 + quad) << 4) ^ kx));
                        c = __builtin_amdgcn_mfma_f32_16x16x32_bf16(a, aq[ks], c, 0, 0, 0);
                    }
                    sc[ctl] = c;
                } else {
                    sc[ctl] = (floatx4){-1e30f, -1e30f, -1e30f, -1e30f};
                }
            }
            __builtin_amdgcn_s_setprio(0);

            // ---- mask + scale ----
            #pragma unroll
            for (int ctl = 0; ctl < 2; ++ctl) {
                if (kt + (2 * gp + ctl) * 16 <= qw + 15) {
                    #pragma unroll
                    for (int r = 0; r < 4; ++r) {
                        const int key = kt + (2 * gp + ctl) * 16 + quad * 4 + r;
                        const bool valid = (key <= qlane) && (key >= ds_lane);
                        float s = sc[ctl][r] * sl;
                        sc[ctl][r] = valid ? s : -1e30f;
                    }
                }
            }

            // ---- online softmax over 8 values + 2 shfl ----
            float mx = fmaxf(fmaxf(fmaxf(sc[0][0], sc[0][1]), fmaxf(sc[0][2], sc[0][3])),
                             fmaxf(fmaxf(sc[1][0], sc[1][1]), fmaxf(sc[1][2], sc[1][3])));
            mx = fmaxf(mx, __shfl_xor(mx, 16, 64));
            mx = fmaxf(mx, __shfl_xor(mx, 32, 64));

            const float mnew = fmaxf(m_r, mx);
            const float al   = exp2f(m_r - mnew);
            const float live = (mnew > -1e29f) ? 1.f : 0.f;  // key-half never valid
            m_r = mnew;

            float ssum = 0.f;
            #pragma unroll
            for (int ctl = 0; ctl < 2; ++ctl) {
                #pragma unroll
                for (int r = 0; r < 4; ++r) {
                    float p = exp2f(sc[ctl][r] - m_r) * live;
                    sc[ctl][r] = p;
                    ssum += p;
                }
            }
            l_r = l_r * al + ssum;
            #pragma unroll
            for (int dt = 0; dt < 8; ++dt) {
                #pragma unroll
                for (int r = 0; r < 4; ++r)
                    oacc[dt][r] *= al;
            }

            // ---- O^T += V^T P^T (this wave's ks = gp only) ----
            union { unsigned u[4]; short8 s; } pu;   // B-frag = own p-values
            pu.u[0] = packbf2(sc[0][0], sc[0][1]);
            pu.u[1] = packbf2(sc[0][2], sc[0][3]);
            pu.u[2] = packbf2(sc[1][0], sc[1][1]);
            pu.u[3] = packbf2(sc[1][2], sc[1][3]);
            __builtin_amdgcn_s_setprio(1);
            #pragma unroll
            for (int dt = 0; dt < 8; ++dt) {
                union { uint4 q; short8 s; } cv;
                cv.q = *(const uint4*)(vbase + (dt * 16 + l16) * 128
                                       + (((gp * 4 + quad) << 4) ^ kx));
                oacc[dt] = __builtin_amdgcn_mfma_f32_16x16x32_bf16(cv.s, pu.s, oacc[dt], 0, 0, 0);
            }
            __builtin_amdgcn_s_setprio(0);
        }

        __syncthreads();   // drains vmcnt (next-tile stage) + readers of buf
    }

    // ---- reduce l over quads (within key-half) ----
    l_r += __shfl_xor(l_r, 16, 64);
    l_r += __shfl_xor(l_r, 32, 64);

    // ---- cross-group merge via LDS (pair = waves wsub, wsub+4) ----
    float* obuf = (float*)&sK[0][0];    // 32KB: 4 pairs x 8KB O-partial
    float* lbuf = (float*)&sVT[0][0];   // m/l: 4 pairs x 128 floats
    if (gp == 1) {
        float* ob = obuf + wsub * 2048;
        #pragma unroll
        for (int dt = 0; dt < 8; ++dt) {
            const int sw = (dt ^ (lane & 7)) << 2;
            float4 st;
            st.x = oacc[dt][0]; st.y = oacc[dt][1];
            st.z = oacc[dt][2]; st.w = oacc[dt][3];
            *(float4*)(ob + lane * 32 + sw) = st;
        }
        if (quad == 0) {
            lbuf[wsub * 128 + l16]      = m_r;
            lbuf[wsub * 128 + 64 + l16] = l_r;
        }
    }
    __syncthreads();
    if (gp == 0) {
        const float m2 = lbuf[wsub * 128 + l16];
        const float l2 = lbuf[wsub * 128 + 64 + l16];
        const float M  = fmaxf(m_r, m2);
        const float w1 = exp2f(m_r - M);
        const float w2 = exp2f(m2 - M);
        const float inv = 1.0f / (w1 * l_r + w2 * l2);
        const float* ob = obuf + wsub * 2048;
        float* op = Oh + (size_t)qlane * HD + quad * 4;
        #pragma unroll
        for (int dt = 0; dt < 8; ++dt) {
            const int sw = (dt ^ (lane & 7)) << 2;
            float4 o2 = *(const float4*)(ob + lane * 32 + sw);
            float4 st;
            st.x = (w1 * oacc[dt][0] + w2 * o2.x) * inv;
            st.y = (w1 * oacc[dt][1] + w2 * o2.y) * inv;
            st.z = (w1 * oacc[dt][2] + w2 * o2.z) * inv;
            st.w = (w1 * oacc[dt][3] + w2 * o2.w) * inv;
            *(float4*)(op + dt * 16) = st;
        }
    }
}

extern "C" void kernel_launch(void* const* d_in, const int* in_sizes, int n_in,
                              void* d_out, int out_size, void* d_ws, size_t ws_size,
                              hipStream_t stream) {
    const float* q = (const float*)d_in[0];
    const float* k = (const float*)d_in[1];
    const float* v = (const float*)d_in[2];
    const int* cu = (const int*)d_in[3];
    const int n_cu = in_sizes[3];
    const int H = 8;
    const int S = in_sizes[0] / (H * HD);   // B=1
    float* out = (float*)d_out;

    const int nqb = S / BR;
    unsigned short* wsK  = (unsigned short*)d_ws;                 // H*S*256 B
    unsigned short* wsVT = wsK + (size_t)H * S * HD;              // H*S*256 B

    const int nVblk = H * (S >> 6);          // 512 (long blocks first)
    const int nKblk = (H * S) / 16;          // 2048
    prepack<<<dim3(nVblk + nKblk), dim3(256), 0, stream>>>(k, v, wsK, wsVT, S);

    dim3 grid(H * nqb);        // 512 blocks, 2 per CU (same-n pairs)
    dim3 block(512);           // 8 waves
    fa_fwd<<<grid, block, 0, stream>>>(q, wsK, wsVT, cu, n_cu, out, S);
}

// Round 7
// 129.387 us; speedup vs baseline: 1.8938x; 1.0466x over previous
//
#include <hip/hip_runtime.h>
#include <hip/hip_bf16.h>

// Flash-attention fwd, block-causal packed docs. fp32 HBM, bf16 MFMA.
// B=1, H=8, D=128. R16 = R15 compute (8-wave key-split, swapped-operand
// QK^T, P-in-registers PV, LDS end-merge) + COUNTED-VMCNT PIPELINE (T3/T4):
//  - R11/R14/R15 all ~47us across wildly different schedules; shared
//    constant = 16 serial tile-steps each ending in __syncthreads() whose
//    implicit s_waitcnt vmcnt(0) drains the gll16 prefetch (m233: 2-phase
//    structure is ~72% stage+vmcnt+barrier overhead). Fix per m218: loads
//    span barriers, vmcnt NEVER drained to 0 inside the loop.
//  - 3 LDS buffers (96KB, 1 block/CU). Per iter t:
//      asm{ s_waitcnt vmcnt(4); s_barrier }   // own stage(t) retired ->
//                                             // barrier -> ALL waves' t done
//      if (t+2<n) stage(t+2, buf[(t+2)%3])    // issued POST-barrier: every
//                                             // wave finished reading that
//                                             // buffer at iter t-1
//      compute(t, buf[t%3])
//    vmcnt(0) only on the final iteration. Reuse distance 3 + <=1-phase
//    barrier skew => race-free (stage target != compute buf of any wave).
//  - grid 512 @ 1 block/CU -> 2 rounds; heavy-first interleaved qb order
//    (ntiles desc) for LPT-style backfill (~17 tile-units/CU).
// Keeps: prepacked bf16 K / key-permuted V^T (XOR-swizzled, gll16 linear
// dest + pre-swizzled src + swizzled read), setprio on MFMA, R15 merge.

#define HD 128
#define BR 64
#define BC 64

typedef __attribute__((ext_vector_type(8))) short short8;
typedef __attribute__((ext_vector_type(4))) float floatx4;

__device__ inline unsigned packbf2(float lo, float hi) {
    __hip_bfloat162 h2 = __float22bfloat162_rn(make_float2(lo, hi));
    return *reinterpret_cast<unsigned*>(&h2);   // low16 = lo, high16 = hi
}
__device__ inline short bfs(float f) {
    __hip_bfloat16 b = __float2bfloat16(f);
    return *reinterpret_cast<short*>(&b);
}

__device__ inline void gll16(const void* g, void* l) {
    __builtin_amdgcn_global_load_lds(
        (const __attribute__((address_space(1))) unsigned int*)g,
        (__attribute__((address_space(3))) unsigned int*)l, 16, 0, 0);
}

// ---------------- prepack: fp32 -> bf16, swizzled (V blocks first) --------
__global__ __launch_bounds__(256) void prepack(
    const float* __restrict__ K, const float* __restrict__ V,
    unsigned short* __restrict__ wsK, unsigned short* __restrict__ wsVT,
    int S)
{
    const int tid = threadIdx.x;
    const int nVblk = 8 * (S >> 6);
    const int bid = blockIdx.x;
    if (bid < nVblk) {
        // V^T via LDS: block = one (h, tile).
        __shared__ __align__(8) unsigned short sV[HD * 68];  // [d][r], stride 68 bf16
        const int ntile = S >> 6;
        const int h = bid / ntile;
        const int t = bid - h * ntile;
        const float* vb = V + ((size_t)h * S + t * 64) * HD;
        {
            const int rp = tid >> 3;
            const int dc = tid & 7;
            const int r0 = rp * 2;
            const int d0 = dc * 16;
            const float* p0 = vb + (size_t)r0 * HD + d0;
            const float* p1 = p0 + HD;
            float4 a0 = *(const float4*)(p0 + 0),  a1 = *(const float4*)(p0 + 4);
            float4 a2 = *(const float4*)(p0 + 8),  a3 = *(const float4*)(p0 + 12);
            float4 b0 = *(const float4*)(p1 + 0),  b1 = *(const float4*)(p1 + 4);
            float4 b2 = *(const float4*)(p1 + 8),  b3 = *(const float4*)(p1 + 12);
            float av[16] = {a0.x,a0.y,a0.z,a0.w, a1.x,a1.y,a1.z,a1.w,
                            a2.x,a2.y,a2.z,a2.w, a3.x,a3.y,a3.z,a3.w};
            float bv[16] = {b0.x,b0.y,b0.z,b0.w, b1.x,b1.y,b1.z,b1.w,
                            b2.x,b2.y,b2.z,b2.w, b3.x,b3.y,b3.z,b3.w};
            #pragma unroll
            for (int i = 0; i < 16; ++i) {
                unsigned pr = packbf2(av[i], bv[i]);   // keys r0 (lo), r0+1 (hi)
                *(unsigned*)((char*)sV + ((size_t)(d0 + i) * 68 + r0) * 2) = pr;
            }
        }
        __syncthreads();
        const int d  = tid >> 1;
        const int jj = tid & 1;
        char* dstrow = (char*)wsVT + (((size_t)(h * ntile + t) * HD + d) * 128);
        const int dx = (d & 7) << 4;
        const unsigned short* srow = sV + (size_t)d * 68;
        #pragma unroll
        for (int u = 0; u < 4; ++u) {
            const int j  = jj * 4 + u;
            const int k0 = (j >> 2) * 32 + (j & 3) * 4;
            uint2 lo = *(const uint2*)(srow + k0);        // keys k0..k0+3
            uint2 hi = *(const uint2*)(srow + k0 + 16);   // keys k0+16..k0+19
            uint4 w = make_uint4(lo.x, lo.y, hi.x, hi.y);
            *(uint4*)(dstrow + ((j * 16) ^ dx)) = w;
        }
    } else {
        // K: one 16B output chunk (8 bf16 <- 8 fp32) per thread, coalesced.
        const int cid = (bid - nVblk) * 256 + tid;
        const int row = cid >> 4;              // global row (h*S + r)
        const int c   = cid & 15;
        const float* src = K + (size_t)row * HD + c * 8;
        float4 f0 = *(const float4*)src;
        float4 f1 = *(const float4*)(src + 4);
        union { uint4 q; unsigned u[4]; } w;
        w.u[0] = packbf2(f0.x, f0.y); w.u[1] = packbf2(f0.z, f0.w);
        w.u[2] = packbf2(f1.x, f1.y); w.u[3] = packbf2(f1.z, f1.w);
        *(uint4*)((char*)wsK + (size_t)row * 256 + ((c * 16) ^ ((row & 7) << 4))) = w.q;
    }
}

// ---------------- main attention kernel ----------------
__global__ __launch_bounds__(512, 1) void fa_fwd(
    const float* __restrict__ Q,
    const unsigned short* __restrict__ wsK,
    const unsigned short* __restrict__ wsVT,
    const int* __restrict__ cu_seqlens, int n_cu,
    float* __restrict__ O,
    int S)
{
    __shared__ alignas(16) __hip_bfloat16 sK3[3][BC * HD];    // 3 x 16KB
    __shared__ alignas(16) unsigned int   sVT3[3][HD * 32];   // 3 x 16KB

    const int tid  = threadIdx.x;
    const int wave = tid >> 6;
    const int gp   = wave >> 2;             // key-half group 0/1
    const int wsub = wave & 3;              // query sub-block 0..3
    const int lane = tid & 63;
    const int quad = lane >> 4;
    const int l16  = lane & 15;
    const int kx   = (l16 & 7) << 4;        // read-side XOR (matches prepack)

    const int nqb = S / BR;
    const int h   = blockIdx.x & 7;
    const int g   = (int)(blockIdx.x >> 3);
    // heavy-first interleaved order: ntiles descending across dispatch
    const int qb = (nqb == 64) ? ((15 - (g >> 2)) + 16 * (g & 3))
                               : (nqb - 1 - g);
    const int q0    = qb * BR;
    const int qw    = q0 + wsub * 16;
    const int qlane = qw + l16;     // the ONE query this lane owns

    // ---- block-uniform doc geometry ----
    int blk_ds = 0;
    for (int i = 0; i < n_cu; ++i) {
        int c = cu_seqlens[i];
        if (c <= q0) blk_ds = c;
    }
    const int k_begin = blk_ds & ~(BC - 1);
    const int ntiles  = (q0 + BR - 1 - k_begin) / BC + 1;

    // ---- staging: 4x global_load_lds dwordx4 per thread (8 waves) ----
    // waves 0-3 stage sK (4KB each), waves 4-7 stage sVT (4KB each).
    const char* gkb = (const char*)wsK + (size_t)h * S * 256;
    const char* gvb = (const char*)wsVT + (size_t)h * (S >> 6) * 16384;
    const int wofs = (wave & 3) * 4096;
    const int lo = wofs + lane * 16;
    auto stage = [&](int kt, int buf) {
        if (gp == 0) {
            const char* gk = gkb + (size_t)kt * 256 + lo;
            char* lk = (char*)&sK3[buf][0] + wofs;         // wave-uniform base
            #pragma unroll
            for (int c = 0; c < 4; ++c) gll16(gk + c * 1024, lk + c * 1024);
        } else {
            const char* gv = gvb + (size_t)(kt >> 6) * 16384 + lo;
            char* lv = (char*)&sVT3[buf][0] + wofs;
            #pragma unroll
            for (int c = 0; c < 4; ++c) gll16(gv + c * 1024, lv + c * 1024);
        }
    };

    const size_t hoff = (size_t)h * S * HD;
    const float* Qh = Q + hoff;
    float*       Oh = O + hoff;

    // ---- Q fragments FIRST (their vmcnt retires before the stages') ----
    short8 aq[4];
    {
        const float* qp = Qh + (size_t)qlane * HD + quad * 8;
        #pragma unroll
        for (int ks = 0; ks < 4; ++ks) {
            float4 a0 = *(const float4*)(qp + ks * 32);
            float4 a1 = *(const float4*)(qp + ks * 32 + 4);
            short8 a;
            a[0] = bfs(a0.x); a[1] = bfs(a0.y); a[2] = bfs(a0.z); a[3] = bfs(a0.w);
            a[4] = bfs(a1.x); a[5] = bfs(a1.y); a[6] = bfs(a1.z); a[7] = bfs(a1.w);
            aq[ks] = a;
        }
    }

    // ---- per-lane doc start ----
    int ds_lane = 0;
    for (int i = 0; i < n_cu; ++i) {
        int c = cu_seqlens[i];
        if (c <= qlane) ds_lane = c;
    }

    // ---- pipeline prologue: stage tiles 0,1 into bufs 0,1 ----
    stage(k_begin, 0);
    if (ntiles > 1) stage(k_begin + BC, 1);

    // oacc[dt][r] = O^T partial for THIS key-half: d=dt*16+quad*4+r, q=qlane
    floatx4 oacc[8];
    #pragma unroll
    for (int dt = 0; dt < 8; ++dt) oacc[dt] = (floatx4){0.f, 0.f, 0.f, 0.f};
    float m_r = -1e30f, l_r = 0.f;

    const float sl = 0.08838834764831845f * 1.4426950408889634f;

    int buf = 0;
    for (int it = 0; it < ntiles; ++it) {
        const int kt = k_begin + it * BC;

        // counted wait: own stage(it) retired (allow stage(it+1)'s 4 in
        // flight), then barrier -> all waves' stage(it) retired. vmcnt(0)
        // only on the last iteration.
        if (it + 1 < ntiles) {
            asm volatile("s_waitcnt vmcnt(4)\n\ts_barrier" ::: "memory");
        } else {
            asm volatile("s_waitcnt vmcnt(0)\n\ts_barrier" ::: "memory");
        }
        __builtin_amdgcn_sched_barrier(0);

        // issue stage(it+2) POST-barrier: its target buffer was last read at
        // iter it-1, which every wave finished before this barrier.
        if (it + 2 < ntiles) {
            int b2 = buf + 2; if (b2 >= 3) b2 -= 3;
            stage(kt + 2 * BC, b2);
        }

        if (kt + gp * 32 <= qw + 15) {       // wave-uniform key-half active
            const char* kbase = (const char*)&sK3[buf][0];
            const char* vbase = (const char*)&sVT3[buf][0];

            // ---- S^T = K Q^T over this wave's 32 keys (2 ct blocks) ----
            floatx4 sc[2];
            __builtin_amdgcn_s_setprio(1);
            #pragma unroll
            for (int ctl = 0; ctl < 2; ++ctl) {
                const int ct = 2 * gp + ctl;
                if (kt + ct * 16 <= qw + 15) {   // wave-uniform
                    floatx4 c = (floatx4){0.f, 0.f, 0.f, 0.f};
                    #pragma unroll
                    for (int ks = 0; ks < 4; ++ks) {
                        short8 a = *(const short8*)(kbase + (ct * 16 + l16) * 256
                                                    + (((ks * 4 + quad) << 4) ^ kx));
                        c = __builtin_amdgcn_mfma_f32_16x16x32_bf16(a, aq[ks], c, 0, 0, 0);
                    }
                    sc[ctl] = c;
                } else {
                    sc[ctl] = (floatx4){-1e30f, -1e30f, -1e30f, -1e30f};
                }
            }
            __builtin_amdgcn_s_setprio(0);

            // ---- mask + scale ----
            #pragma unroll
            for (int ctl = 0; ctl < 2; ++ctl) {
                if (kt + (2 * gp + ctl) * 16 <= qw + 15) {
                    #pragma unroll
                    for (int r = 0; r < 4; ++r) {
                        const int key = kt + (2 * gp + ctl) * 16 + quad * 4 + r;
                        const bool valid = (key <= qlane) && (key >= ds_lane);
                        float s = sc[ctl][r] * sl;
                        sc[ctl][r] = valid ? s : -1e30f;
                    }
                }
            }

            // ---- online softmax over 8 values + 2 shfl ----
            float mx = fmaxf(fmaxf(fmaxf(sc[0][0], sc[0][1]), fmaxf(sc[0][2], sc[0][3])),
                             fmaxf(fmaxf(sc[1][0], sc[1][1]), fmaxf(sc[1][2], sc[1][3])));
            mx = fmaxf(mx, __shfl_xor(mx, 16, 64));
            mx = fmaxf(mx, __shfl_xor(mx, 32, 64));

            const float mnew = fmaxf(m_r, mx);
            const float al   = exp2f(m_r - mnew);
            const float live = (mnew > -1e29f) ? 1.f : 0.f;  // key-half never valid
            m_r = mnew;

            float ssum = 0.f;
            #pragma unroll
            for (int ctl = 0; ctl < 2; ++ctl) {
                #pragma unroll
                for (int r = 0; r < 4; ++r) {
                    float p = exp2f(sc[ctl][r] - m_r) * live;
                    sc[ctl][r] = p;
                    ssum += p;
                }
            }
            l_r = l_r * al + ssum;
            #pragma unroll
            for (int dt = 0; dt < 8; ++dt) {
                #pragma unroll
                for (int r = 0; r < 4; ++r)
                    oacc[dt][r] *= al;
            }

            // ---- O^T += V^T P^T (this wave's ks = gp only) ----
            union { unsigned u[4]; short8 s; } pu;   // B-frag = own p-values
            pu.u[0] = packbf2(sc[0][0], sc[0][1]);
            pu.u[1] = packbf2(sc[0][2], sc[0][3]);
            pu.u[2] = packbf2(sc[1][0], sc[1][1]);
            pu.u[3] = packbf2(sc[1][2], sc[1][3]);
            __builtin_amdgcn_s_setprio(1);
            #pragma unroll
            for (int dt = 0; dt < 8; ++dt) {
                union { uint4 q; short8 s; } cv;
                cv.q = *(const uint4*)(vbase + (dt * 16 + l16) * 128
                                       + (((gp * 4 + quad) << 4) ^ kx));
                oacc[dt] = __builtin_amdgcn_mfma_f32_16x16x32_bf16(cv.s, pu.s, oacc[dt], 0, 0, 0);
            }
            __builtin_amdgcn_s_setprio(0);
        }

        ++buf; if (buf >= 3) buf = 0;
    }

    // ---- reduce l over quads (within key-half) ----
    l_r += __shfl_xor(l_r, 16, 64);
    l_r += __shfl_xor(l_r, 32, 64);

    __syncthreads();    // all compute done before LDS reuse (full drain OK here)

    // ---- cross-group merge via LDS (pair = waves wsub, wsub+4) ----
    float* obuf = (float*)&sK3[0][0];    // 32KB: 4 pairs x 8KB O-partial
    float* lbuf = (float*)&sVT3[0][0];   // m/l: 4 pairs x 128 floats
    if (gp == 1) {
        float* ob = obuf + wsub * 2048;
        #pragma unroll
        for (int dt = 0; dt < 8; ++dt) {
            const int sw = (dt ^ (lane & 7)) << 2;
            float4 st;
            st.x = oacc[dt][0]; st.y = oacc[dt][1];
            st.z = oacc[dt][2]; st.w = oacc[dt][3];
            *(float4*)(ob + lane * 32 + sw) = st;
        }
        if (quad == 0) {
            lbuf[wsub * 128 + l16]      = m_r;
            lbuf[wsub * 128 + 64 + l16] = l_r;
        }
    }
    __syncthreads();
    if (gp == 0) {
        const float m2 = lbuf[wsub * 128 + l16];
        const float l2 = lbuf[wsub * 128 + 64 + l16];
        const float M  = fmaxf(m_r, m2);
        const float w1 = exp2f(m_r - M);
        const float w2 = exp2f(m2 - M);
        const float inv = 1.0f / (w1 * l_r + w2 * l2);
        const float* ob = obuf + wsub * 2048;
        float* op = Oh + (size_t)qlane * HD + quad * 4;
        #pragma unroll
        for (int dt = 0; dt < 8; ++dt) {
            const int sw = (dt ^ (lane & 7)) << 2;
            float4 o2 = *(const float4*)(ob + lane * 32 + sw);
            float4 st;
            st.x = (w1 * oacc[dt][0] + w2 * o2.x) * inv;
            st.y = (w1 * oacc[dt][1] + w2 * o2.y) * inv;
            st.z = (w1 * oacc[dt][2] + w2 * o2.z) * inv;
            st.w = (w1 * oacc[dt][3] + w2 * o2.w) * inv;
            *(float4*)(op + dt * 16) = st;
        }
    }
}

extern "C" void kernel_launch(void* const* d_in, const int* in_sizes, int n_in,
                              void* d_out, int out_size, void* d_ws, size_t ws_size,
                              hipStream_t stream) {
    const float* q = (const float*)d_in[0];
    const float* k = (const float*)d_in[1];
    const float* v = (const float*)d_in[2];
    const int* cu = (const int*)d_in[3];
    const int n_cu = in_sizes[3];
    const int H = 8;
    const int S = in_sizes[0] / (H * HD);   // B=1
    float* out = (float*)d_out;

    const int nqb = S / BR;
    unsigned short* wsK  = (unsigned short*)d_ws;                 // H*S*256 B
    unsigned short* wsVT = wsK + (size_t)H * S * HD;              // H*S*256 B

    const int nVblk = H * (S >> 6);          // 512 (long blocks first)
    const int nKblk = (H * S) / 16;          // 2048
    prepack<<<dim3(nVblk + nKblk), dim3(256), 0, stream>>>(k, v, wsK, wsVT, S);

    dim3 grid(H * nqb);        // 512 blocks, 1 per CU resident (96KB LDS)
    dim3 block(512);           // 8 waves
    fa_fwd<<<grid, block, 0, stream>>>(q, wsK, wsVT, cu, n_cu, out, S);
}

// Round 8
// 128.555 us; speedup vs baseline: 1.9060x; 1.0065x over previous
//
#include <hip/hip_runtime.h>
#include <hip/hip_bf16.h>

// Flash-attention fwd, block-causal packed docs. fp32 HBM, bf16 MFMA.
// B=1, H=8, D=128. R17 = R16 (8-wave key-split, counted-vmcnt 3-buffer
// pipeline, 42.4us) + T13 DEFER-RESCALE + scheduler unpinning:
//  - R16 counters: VALUBusy*dur/steps ~= 450 VALU instr/wave/tile vs ~180
//    written => per-tile `oacc *= al` (32 AGPR-resident elems) forces
//    accvgpr_read/mul/write round-trips + serial stage between softmax and
//    PV (oacc is PV's C operand), every tile. T13: rescale only when
//    __any(mx > m_r + 8) — p bounded by 2^8, fp32 accum headroom ample;
//    ~90% of tiles skip rescale entirely (tile-max drift << 8 after warmup).
//    live-guard still zeroes never-valid lanes (m_r stays -1e30 on defer).
//  - removed sched_barrier(0) after wait+barrier asm: "memory" clobber
//    already orders ds_reads/gll16 across it (rule 18 n/a — no lgkmcnt asm);
//    pinning blocked PV V-tile ds_read hoisting into softmax (m141 lesson).
// Keeps from R16: 3 LDS buffers (96KB, 1 block/CU), per-iter
// {s_waitcnt vmcnt(4); s_barrier} then post-barrier stage(t+2) — loads span
// barriers, vmcnt(0) only on last iter; heavy-first LPT order (~17
// tile-units/CU makespan); swapped-operand QK^T; P-in-registers PV;
// prepacked bf16 K / key-permuted V^T (XOR-swizzle both sides, gll16 linear
// dest); LDS end-merge of the two key-half groups; setprio on MFMA.

#define HD 128
#define BR 64
#define BC 64

typedef __attribute__((ext_vector_type(8))) short short8;
typedef __attribute__((ext_vector_type(4))) float floatx4;

__device__ inline unsigned packbf2(float lo, float hi) {
    __hip_bfloat162 h2 = __float22bfloat162_rn(make_float2(lo, hi));
    return *reinterpret_cast<unsigned*>(&h2);   // low16 = lo, high16 = hi
}
__device__ inline short bfs(float f) {
    __hip_bfloat16 b = __float2bfloat16(f);
    return *reinterpret_cast<short*>(&b);
}

__device__ inline void gll16(const void* g, void* l) {
    __builtin_amdgcn_global_load_lds(
        (const __attribute__((address_space(1))) unsigned int*)g,
        (__attribute__((address_space(3))) unsigned int*)l, 16, 0, 0);
}

// ---------------- prepack: fp32 -> bf16, swizzled (V blocks first) --------
__global__ __launch_bounds__(256) void prepack(
    const float* __restrict__ K, const float* __restrict__ V,
    unsigned short* __restrict__ wsK, unsigned short* __restrict__ wsVT,
    int S)
{
    const int tid = threadIdx.x;
    const int nVblk = 8 * (S >> 6);
    const int bid = blockIdx.x;
    if (bid < nVblk) {
        // V^T via LDS: block = one (h, tile).
        __shared__ __align__(8) unsigned short sV[HD * 68];  // [d][r], stride 68 bf16
        const int ntile = S >> 6;
        const int h = bid / ntile;
        const int t = bid - h * ntile;
        const float* vb = V + ((size_t)h * S + t * 64) * HD;
        {
            const int rp = tid >> 3;
            const int dc = tid & 7;
            const int r0 = rp * 2;
            const int d0 = dc * 16;
            const float* p0 = vb + (size_t)r0 * HD + d0;
            const float* p1 = p0 + HD;
            float4 a0 = *(const float4*)(p0 + 0),  a1 = *(const float4*)(p0 + 4);
            float4 a2 = *(const float4*)(p0 + 8),  a3 = *(const float4*)(p0 + 12);
            float4 b0 = *(const float4*)(p1 + 0),  b1 = *(const float4*)(p1 + 4);
            float4 b2 = *(const float4*)(p1 + 8),  b3 = *(const float4*)(p1 + 12);
            float av[16] = {a0.x,a0.y,a0.z,a0.w, a1.x,a1.y,a1.z,a1.w,
                            a2.x,a2.y,a2.z,a2.w, a3.x,a3.y,a3.z,a3.w};
            float bv[16] = {b0.x,b0.y,b0.z,b0.w, b1.x,b1.y,b1.z,b1.w,
                            b2.x,b2.y,b2.z,b2.w, b3.x,b3.y,b3.z,b3.w};
            #pragma unroll
            for (int i = 0; i < 16; ++i) {
                unsigned pr = packbf2(av[i], bv[i]);   // keys r0 (lo), r0+1 (hi)
                *(unsigned*)((char*)sV + ((size_t)(d0 + i) * 68 + r0) * 2) = pr;
            }
        }
        __syncthreads();
        const int d  = tid >> 1;
        const int jj = tid & 1;
        char* dstrow = (char*)wsVT + (((size_t)(h * ntile + t) * HD + d) * 128);
        const int dx = (d & 7) << 4;
        const unsigned short* srow = sV + (size_t)d * 68;
        #pragma unroll
        for (int u = 0; u < 4; ++u) {
            const int j  = jj * 4 + u;
            const int k0 = (j >> 2) * 32 + (j & 3) * 4;
            uint2 lo = *(const uint2*)(srow + k0);        // keys k0..k0+3
            uint2 hi = *(const uint2*)(srow + k0 + 16);   // keys k0+16..k0+19
            uint4 w = make_uint4(lo.x, lo.y, hi.x, hi.y);
            *(uint4*)(dstrow + ((j * 16) ^ dx)) = w;
        }
    } else {
        // K: one 16B output chunk (8 bf16 <- 8 fp32) per thread, coalesced.
        const int cid = (bid - nVblk) * 256 + tid;
        const int row = cid >> 4;              // global row (h*S + r)
        const int c   = cid & 15;
        const float* src = K + (size_t)row * HD + c * 8;
        float4 f0 = *(const float4*)src;
        float4 f1 = *(const float4*)(src + 4);
        union { uint4 q; unsigned u[4]; } w;
        w.u[0] = packbf2(f0.x, f0.y); w.u[1] = packbf2(f0.z, f0.w);
        w.u[2] = packbf2(f1.x, f1.y); w.u[3] = packbf2(f1.z, f1.w);
        *(uint4*)((char*)wsK + (size_t)row * 256 + ((c * 16) ^ ((row & 7) << 4))) = w.q;
    }
}

// ---------------- main attention kernel ----------------
__global__ __launch_bounds__(512, 1) void fa_fwd(
    const float* __restrict__ Q,
    const unsigned short* __restrict__ wsK,
    const unsigned short* __restrict__ wsVT,
    const int* __restrict__ cu_seqlens, int n_cu,
    float* __restrict__ O,
    int S)
{
    __shared__ alignas(16) __hip_bfloat16 sK3[3][BC * HD];    // 3 x 16KB
    __shared__ alignas(16) unsigned int   sVT3[3][HD * 32];   // 3 x 16KB

    const int tid  = threadIdx.x;
    const int wave = tid >> 6;
    const int gp   = wave >> 2;             // key-half group 0/1
    const int wsub = wave & 3;              // query sub-block 0..3
    const int lane = tid & 63;
    const int quad = lane >> 4;
    const int l16  = lane & 15;
    const int kx   = (l16 & 7) << 4;        // read-side XOR (matches prepack)

    const int nqb = S / BR;
    const int h   = blockIdx.x & 7;
    const int g   = (int)(blockIdx.x >> 3);
    // heavy-first interleaved order: ntiles descending across dispatch
    const int qb = (nqb == 64) ? ((15 - (g >> 2)) + 16 * (g & 3))
                               : (nqb - 1 - g);
    const int q0    = qb * BR;
    const int qw    = q0 + wsub * 16;
    const int qlane = qw + l16;     // the ONE query this lane owns

    // ---- block-uniform doc geometry ----
    int blk_ds = 0;
    for (int i = 0; i < n_cu; ++i) {
        int c = cu_seqlens[i];
        if (c <= q0) blk_ds = c;
    }
    const int k_begin = blk_ds & ~(BC - 1);
    const int ntiles  = (q0 + BR - 1 - k_begin) / BC + 1;

    // ---- staging: 4x global_load_lds dwordx4 per thread (8 waves) ----
    // waves 0-3 stage sK (4KB each), waves 4-7 stage sVT (4KB each).
    const char* gkb = (const char*)wsK + (size_t)h * S * 256;
    const char* gvb = (const char*)wsVT + (size_t)h * (S >> 6) * 16384;
    const int wofs = (wave & 3) * 4096;
    const int lo = wofs + lane * 16;
    auto stage = [&](int kt, int buf) {
        if (gp == 0) {
            const char* gk = gkb + (size_t)kt * 256 + lo;
            char* lk = (char*)&sK3[buf][0] + wofs;         // wave-uniform base
            #pragma unroll
            for (int c = 0; c < 4; ++c) gll16(gk + c * 1024, lk + c * 1024);
        } else {
            const char* gv = gvb + (size_t)(kt >> 6) * 16384 + lo;
            char* lv = (char*)&sVT3[buf][0] + wofs;
            #pragma unroll
            for (int c = 0; c < 4; ++c) gll16(gv + c * 1024, lv + c * 1024);
        }
    };

    const size_t hoff = (size_t)h * S * HD;
    const float* Qh = Q + hoff;
    float*       Oh = O + hoff;

    // ---- Q fragments FIRST (their vmcnt retires before the stages') ----
    short8 aq[4];
    {
        const float* qp = Qh + (size_t)qlane * HD + quad * 8;
        #pragma unroll
        for (int ks = 0; ks < 4; ++ks) {
            float4 a0 = *(const float4*)(qp + ks * 32);
            float4 a1 = *(const float4*)(qp + ks * 32 + 4);
            short8 a;
            a[0] = bfs(a0.x); a[1] = bfs(a0.y); a[2] = bfs(a0.z); a[3] = bfs(a0.w);
            a[4] = bfs(a1.x); a[5] = bfs(a1.y); a[6] = bfs(a1.z); a[7] = bfs(a1.w);
            aq[ks] = a;
        }
    }

    // ---- per-lane doc start ----
    int ds_lane = 0;
    for (int i = 0; i < n_cu; ++i) {
        int c = cu_seqlens[i];
        if (c <= qlane) ds_lane = c;
    }

    // ---- pipeline prologue: stage tiles 0,1 into bufs 0,1 ----
    stage(k_begin, 0);
    if (ntiles > 1) stage(k_begin + BC, 1);

    // oacc[dt][r] = O^T partial for THIS key-half: d=dt*16+quad*4+r, q=qlane
    floatx4 oacc[8];
    #pragma unroll
    for (int dt = 0; dt < 8; ++dt) oacc[dt] = (floatx4){0.f, 0.f, 0.f, 0.f};
    float m_r = -1e30f, l_r = 0.f;

    const float sl = 0.08838834764831845f * 1.4426950408889634f;

    int buf = 0;
    for (int it = 0; it < ntiles; ++it) {
        const int kt = k_begin + it * BC;

        // counted wait: own stage(it) retired (allow stage(it+1)'s 4 in
        // flight), then barrier -> all waves' stage(it) retired. vmcnt(0)
        // only on the last iteration.
        if (it + 1 < ntiles) {
            asm volatile("s_waitcnt vmcnt(4)\n\ts_barrier" ::: "memory");
        } else {
            asm volatile("s_waitcnt vmcnt(0)\n\ts_barrier" ::: "memory");
        }

        // issue stage(it+2) POST-barrier: its target buffer was last read at
        // iter it-1, which every wave finished before this barrier.
        if (it + 2 < ntiles) {
            int b2 = buf + 2; if (b2 >= 3) b2 -= 3;
            stage(kt + 2 * BC, b2);
        }

        if (kt + gp * 32 <= qw + 15) {       // wave-uniform key-half active
            const char* kbase = (const char*)&sK3[buf][0];
            const char* vbase = (const char*)&sVT3[buf][0];

            // ---- S^T = K Q^T over this wave's 32 keys (2 ct blocks) ----
            floatx4 sc[2];
            __builtin_amdgcn_s_setprio(1);
            #pragma unroll
            for (int ctl = 0; ctl < 2; ++ctl) {
                const int ct = 2 * gp + ctl;
                if (kt + ct * 16 <= qw + 15) {   // wave-uniform
                    floatx4 c = (floatx4){0.f, 0.f, 0.f, 0.f};
                    #pragma unroll
                    for (int ks = 0; ks < 4; ++ks) {
                        short8 a = *(const short8*)(kbase + (ct * 16 + l16) * 256
                                                    + (((ks * 4 + quad) << 4) ^ kx));
                        c = __builtin_amdgcn_mfma_f32_16x16x32_bf16(a, aq[ks], c, 0, 0, 0);
                    }
                    sc[ctl] = c;
                } else {
                    sc[ctl] = (floatx4){-1e30f, -1e30f, -1e30f, -1e30f};
                }
            }
            __builtin_amdgcn_s_setprio(0);

            // ---- mask + scale ----
            #pragma unroll
            for (int ctl = 0; ctl < 2; ++ctl) {
                if (kt + (2 * gp + ctl) * 16 <= qw + 15) {
                    #pragma unroll
                    for (int r = 0; r < 4; ++r) {
                        const int key = kt + (2 * gp + ctl) * 16 + quad * 4 + r;
                        const bool valid = (key <= qlane) && (key >= ds_lane);
                        float s = sc[ctl][r] * sl;
                        sc[ctl][r] = valid ? s : -1e30f;
                    }
                }
            }

            // ---- online softmax over 8 values + 2 shfl ----
            float mx = fmaxf(fmaxf(fmaxf(sc[0][0], sc[0][1]), fmaxf(sc[0][2], sc[0][3])),
                             fmaxf(fmaxf(sc[1][0], sc[1][1]), fmaxf(sc[1][2], sc[1][3])));
            mx = fmaxf(mx, __shfl_xor(mx, 16, 64));
            mx = fmaxf(mx, __shfl_xor(mx, 32, 64));

            // T13 defer-rescale: skip the oacc/l rescale (32 AGPR-resident
            // muls + serial stage before PV) unless some lane's tile-max
            // exceeds m_r + 8. p bounded by 2^8; fp32 accum headroom ample.
            if (__any(mx > m_r + 8.f)) {
                const float mnew = fmaxf(m_r, mx);
                const float al   = exp2f(m_r - mnew);
                m_r = mnew;
                l_r *= al;
                #pragma unroll
                for (int dt = 0; dt < 8; ++dt) {
                    #pragma unroll
                    for (int r = 0; r < 4; ++r)
                        oacc[dt][r] *= al;
                }
            }
            const float live = (m_r > -1e29f) ? 1.f : 0.f;  // key-half never valid

            float ssum = 0.f;
            #pragma unroll
            for (int ctl = 0; ctl < 2; ++ctl) {
                #pragma unroll
                for (int r = 0; r < 4; ++r) {
                    float p = exp2f(sc[ctl][r] - m_r) * live;
                    sc[ctl][r] = p;
                    ssum += p;
                }
            }
            l_r += ssum;

            // ---- O^T += V^T P^T (this wave's ks = gp only) ----
            union { unsigned u[4]; short8 s; } pu;   // B-frag = own p-values
            pu.u[0] = packbf2(sc[0][0], sc[0][1]);
            pu.u[1] = packbf2(sc[0][2], sc[0][3]);
            pu.u[2] = packbf2(sc[1][0], sc[1][1]);
            pu.u[3] = packbf2(sc[1][2], sc[1][3]);
            __builtin_amdgcn_s_setprio(1);
            #pragma unroll
            for (int dt = 0; dt < 8; ++dt) {
                union { uint4 q; short8 s; } cv;
                cv.q = *(const uint4*)(vbase + (dt * 16 + l16) * 128
                                       + (((gp * 4 + quad) << 4) ^ kx));
                oacc[dt] = __builtin_amdgcn_mfma_f32_16x16x32_bf16(cv.s, pu.s, oacc[dt], 0, 0, 0);
            }
            __builtin_amdgcn_s_setprio(0);
        }

        ++buf; if (buf >= 3) buf = 0;
    }

    // ---- reduce l over quads (within key-half) ----
    l_r += __shfl_xor(l_r, 16, 64);
    l_r += __shfl_xor(l_r, 32, 64);

    __syncthreads();    // all compute done before LDS reuse (full drain OK here)

    // ---- cross-group merge via LDS (pair = waves wsub, wsub+4) ----
    // exact regardless of whether m_r is the true max (reference-point
    // identity: w = exp2(m_r - M), l/oacc are relative to m_r).
    float* obuf = (float*)&sK3[0][0];    // 32KB: 4 pairs x 8KB O-partial
    float* lbuf = (float*)&sVT3[0][0];   // m/l: 4 pairs x 128 floats
    if (gp == 1) {
        float* ob = obuf + wsub * 2048;
        #pragma unroll
        for (int dt = 0; dt < 8; ++dt) {
            const int sw = (dt ^ (lane & 7)) << 2;
            float4 st;
            st.x = oacc[dt][0]; st.y = oacc[dt][1];
            st.z = oacc[dt][2]; st.w = oacc[dt][3];
            *(float4*)(ob + lane * 32 + sw) = st;
        }
        if (quad == 0) {
            lbuf[wsub * 128 + l16]      = m_r;
            lbuf[wsub * 128 + 64 + l16] = l_r;
        }
    }
    __syncthreads();
    if (gp == 0) {
        const float m2 = lbuf[wsub * 128 + l16];
        const float l2 = lbuf[wsub * 128 + 64 + l16];
        const float M  = fmaxf(m_r, m2);
        const float w1 = exp2f(m_r - M);
        const float w2 = exp2f(m2 - M);
        const float inv = 1.0f / (w1 * l_r + w2 * l2);
        const float* ob = obuf + wsub * 2048;
        float* op = Oh + (size_t)qlane * HD + quad * 4;
        #pragma unroll
        for (int dt = 0; dt < 8; ++dt) {
            const int sw = (dt ^ (lane & 7)) << 2;
            float4 o2 = *(const float4*)(ob + lane * 32 + sw);
            float4 st;
            st.x = (w1 * oacc[dt][0] + w2 * o2.x) * inv;
            st.y = (w1 * oacc[dt][1] + w2 * o2.y) * inv;
            st.z = (w1 * oacc[dt][2] + w2 * o2.z) * inv;
            st.w = (w1 * oacc[dt][3] + w2 * o2.w) * inv;
            *(float4*)(op + dt * 16) = st;
        }
    }
}

extern "C" void kernel_launch(void* const* d_in, const int* in_sizes, int n_in,
                              void* d_out, int out_size, void* d_ws, size_t ws_size,
                              hipStream_t stream) {
    const float* q = (const float*)d_in[0];
    const float* k = (const float*)d_in[1];
    const float* v = (const float*)d_in[2];
    const int* cu = (const int*)d_in[3];
    const int n_cu = in_sizes[3];
    const int H = 8;
    const int S = in_sizes[0] / (H * HD);   // B=1
    float* out = (float*)d_out;

    const int nqb = S / BR;
    unsigned short* wsK  = (unsigned short*)d_ws;                 // H*S*256 B
    unsigned short* wsVT = wsK + (size_t)H * S * HD;              // H*S*256 B

    const int nVblk = H * (S >> 6);          // 512 (long blocks first)
    const int nKblk = (H * S) / 16;          // 2048
    prepack<<<dim3(nVblk + nKblk), dim3(256), 0, stream>>>(k, v, wsK, wsVT, S);

    dim3 grid(H * nqb);        // 512 blocks, 1 per CU resident (96KB LDS)
    dim3 block(512);           // 8 waves
    fa_fwd<<<grid, block, 0, stream>>>(q, wsK, wsVT, cu, n_cu, out, S);
}